// Round 8
// baseline (993.495 us; speedup 1.0000x reference)
//
#include <hip/hip_runtime.h>
#include <hip/hip_bf16.h>
#include <math.h>

#define B_ 32
#define S_ 128
#define C_ 384
#define H_ 8
#define W_ 512
#define NKV 4096   // H_*W_

typedef __attribute__((ext_vector_type(8))) short short8;
typedef __attribute__((ext_vector_type(4))) float floatx4;

static __device__ __forceinline__ ushort f2bf(float v) {
    __hip_bfloat16 h = __float2bfloat16(v);
    return *(ushort*)&h;
}
static __device__ __forceinline__ float ldf(const float* p, size_t i) { return p[i]; }
static __device__ __forceinline__ float ldf(const ushort* p, size_t i) {
    union { uint u; float f; } c; c.u = (uint)p[i] << 16; return c.f;
}

// ------------------------------------------- hand-rolled grid barrier
// Sense-reversing, generation-counted. Device-scope atomics + threadfence —
// the same primitive ROCm's cooperative grid.sync uses. Requires all blocks
// resident (guaranteed: grid=512 = 2 blocks/CU x 256 CU, launch_bounds(256,2)).
static __device__ __forceinline__ void gridbar(uint* cnt, uint* gen, uint nb) {
    __syncthreads();
    if (threadIdx.x == 0) {
        __threadfence();
        uint g = atomicAdd(gen, 0u);
        uint old = atomicAdd(cnt, 1u);
        if (old == nb - 1u) {
            atomicExch(cnt, 0u);
            __threadfence();
            atomicAdd(gen, 1u);
        } else {
            while (atomicAdd(gen, 0u) == g) { __builtin_amdgcn_s_sleep(8); }
        }
        __threadfence();
    }
    __syncthreads();
}

// ------------------------------------------- merged prep: mean, q cast, weight trans
struct PrepDesc {
    const float* kv; ushort* dec0b; const float* q; ushort* qb;
    const float* wsrc[12]; ushort* wdst[12]; int wN[12];
};
__global__ __launch_bounds__(256) void prep2_kernel(PrepDesc d) {
    __shared__ float t[32][33];
    const int meanB = B_ * W_ * (C_ / 4) / 256;   // 6144
    const int castB = B_ * S_ * (C_ / 4) / 256;   // 1536
    int bid = blockIdx.x;
    int tid = threadIdx.x;
    if (bid < meanB) {
        int v = bid * 256 + tid;
        int c4  = v % (C_ / 4);
        int row = v / (C_ / 4);
        int b = row / W_;
        int w = row % W_;
        const float4* src = (const float4*)d.kv + (size_t)(b * NKV + w) * (C_ / 4) + c4;
        float4 s = {0.f, 0.f, 0.f, 0.f};
#pragma unroll
        for (int h = 0; h < H_; ++h) {
            float4 x = src[(size_t)h * W_ * (C_ / 4)];
            s.x += x.x; s.y += x.y; s.z += x.z; s.w += x.w;
        }
        ushort4 o;
        o.x = f2bf(s.x * 0.125f); o.y = f2bf(s.y * 0.125f);
        o.z = f2bf(s.z * 0.125f); o.w = f2bf(s.w * 0.125f);
        ((ushort4*)d.dec0b)[v] = o;
        return;
    }
    if (bid < meanB + castB) {
        int v = (bid - meanB) * 256 + tid;
        float4 f = ((const float4*)d.q)[v];
        ushort4 o;
        o.x = f2bf(f.x); o.y = f2bf(f.y); o.z = f2bf(f.z); o.w = f2bf(f.w);
        ((ushort4*)d.qb)[v] = o;
        return;
    }
    int f = bid - meanB - castB;          // 0..3455
    int wi = f / 288, tile = f % 288;
    int N = d.wN[wi];
    int tiles_n = N / 32;
    if (tile >= 12 * tiles_n) return;     // K/32 == 12
    int k0 = (tile / tiles_n) * 32, n0 = (tile % tiles_n) * 32;
    int r = tid >> 3, c4 = (tid & 7) * 4;
    float4 v = *(const float4*)&d.wsrc[wi][(size_t)(k0 + r) * N + n0 + c4];
    t[r][c4] = v.x; t[r][c4 + 1] = v.y; t[r][c4 + 2] = v.z; t[r][c4 + 3] = v.w;
    __syncthreads();
    int c = tid >> 3, k4 = (tid & 7) * 4;
    ushort4 o;
    o.x = f2bf(t[k4][c]); o.y = f2bf(t[k4 + 1][c]);
    o.z = f2bf(t[k4 + 2][c]); o.w = f2bf(t[k4 + 3][c]);
    *(ushort4*)&d.wdst[wi][(size_t)(n0 + c) * 384 + k0 + k4] = o;
}

// ---------------------------------------------------------------- bf16 MFMA GEMM 128x128
// Reg-staged 128x128 + job table (up to 3 GEMMs / dispatch) + K-loop software pipeline.
struct GJob {
    const ushort* A; const ushort* Bt;
    const float* bias; float* Cout; ushort* Cbf;
    int M, N, K; float alpha; int act;
};
struct GJobs { GJob j[3]; };

__global__ __launch_bounds__(256) void bgemm_kernel(GJobs gs) {
    const GJob g = gs.j[blockIdx.z];
    const int bm = blockIdx.y * 128, bn = blockIdx.x * 128;
    if (bm >= g.M || bn >= g.N) return;
    __shared__ ushort As[128 * 40];
    __shared__ ushort Bs[128 * 40];
    const int tid = threadIdx.x;
    const int wav = tid >> 6, lane = tid & 63;
    const int wm = (wav >> 1) * 64, wn = (wav & 1) * 64;
    const int lrow = lane & 15, lq = lane >> 4;

    floatx4 acc[4][4] = {};

    const int sr = tid >> 1, sc0 = (tid & 1) * 16;
    const ushort* Ag = g.A + (size_t)(bm + sr) * g.K + sc0;
    const ushort* Bg = g.Bt + (size_t)(bn + sr) * g.K + sc0;
    ushort* Asw = &As[sr * 40 + sc0];
    ushort* Bsw = &Bs[sr * 40 + sc0];

    uint4 a0 = *(const uint4*)(Ag);
    uint4 a1 = *(const uint4*)(Ag + 8);
    uint4 b0 = *(const uint4*)(Bg);
    uint4 b1 = *(const uint4*)(Bg + 8);

    for (int k0 = 0; k0 < g.K; k0 += 32) {
        __syncthreads();
        *(uint4*)Asw = a0; *(uint4*)(Asw + 8) = a1;
        *(uint4*)Bsw = b0; *(uint4*)(Bsw + 8) = b1;
        __syncthreads();
        if (k0 + 32 < g.K) {
            a0 = *(const uint4*)(Ag + k0 + 32);
            a1 = *(const uint4*)(Ag + k0 + 40);
            b0 = *(const uint4*)(Bg + k0 + 32);
            b1 = *(const uint4*)(Bg + k0 + 40);
        }
        short8 af[4], bfr[4];
#pragma unroll
        for (int i = 0; i < 4; ++i)
            af[i] = *(const short8*)&As[(wm + 16 * i + lrow) * 40 + lq * 8];
#pragma unroll
        for (int j = 0; j < 4; ++j)
            bfr[j] = *(const short8*)&Bs[(wn + 16 * j + lrow) * 40 + lq * 8];
#pragma unroll
        for (int i = 0; i < 4; ++i)
#pragma unroll
            for (int j = 0; j < 4; ++j)
                acc[i][j] = __builtin_amdgcn_mfma_f32_16x16x32_bf16(af[i], bfr[j], acc[i][j], 0, 0, 0);
    }

#pragma unroll
    for (int i = 0; i < 4; ++i)
#pragma unroll
        for (int j = 0; j < 4; ++j) {
            int row = bm + wm + 16 * i + lq * 4;
            int col = bn + wn + 16 * j + lrow;
            float bv = g.bias ? g.bias[col] : 0.f;
#pragma unroll
            for (int r = 0; r < 4; ++r) {
                float v = acc[i][j][r] * g.alpha + bv;
                if (g.act == 1) v = tanhf(v);
                size_t off = (size_t)(row + r) * g.N + col;
                if (g.Cout) g.Cout[off] = v;
                if (g.Cbf) g.Cbf[off] = f2bf(v);
            }
        }
}

static inline void bgemmJ(hipStream_t st, int nj, const GJob* js) {
    GJobs gs;
    int mx = 0, my = 0;
    for (int i = 0; i < nj; ++i) {
        gs.j[i] = js[i];
        int nx = js[i].N / 128, ny = js[i].M / 128;
        if (nx > mx) mx = nx;
        if (ny > my) my = ny;
    }
    for (int i = nj; i < 3; ++i) gs.j[i] = js[0];
    bgemm_kernel<<<dim3(mx, my, nj), 256, 0, st>>>(gs);
}

// ------------------------------------------- generic batched 64x64 MFMA GEMM unit
// (+ fused 32x32 v-transpose tiles and fused p_t-head reductions, flat z-packed)
struct BGArgs {
    const ushort* A; const ushort* Bt;
    const float* bias; float* outF; ushort* outB;
    int lda, ldb, ldo;
    long AsB, BsB, OsB;
    int AsH, BsH, OsH;
    int K, NH;
    float alpha; int act;
    int nbat, vtz;
    const ushort* vtsrc; ushort* vtdst; int vtNw;
    const float* ptT; const float* vpw; const float* vpb; float* ptout; int ptrows;
};

static __device__ void battn_unit(const BGArgs& g, int u, int gx, int gy) {
    __shared__ ushort As[64 * 40];
    __shared__ ushort Bs[64 * 40];
    const int per = gx * gy;
    const int bat = u / per;
    const int bxy = u % per;
    const int bx = bxy % gx, by = bxy / gx;
    const int tid = threadIdx.x;
    if (bat >= g.nbat) {
        if (bat < g.nbat + g.vtz) {
            // -------- fused v-transpose tile: src (B*Nw,768) v-part -> vt (B,384,Nw)
            int flat = (bat - g.nbat) * per + bxy;
            int wt_n = g.vtNw >> 5;
            int tiles = wt_n * (C_ / 32);
            if (flat < B_ * tiles) {
                int b  = flat / tiles, rr = flat % tiles;
                int w0 = (rr % wt_n) * 32, c0 = (rr / wt_n) * 32;
                ushort (*t)[33] = (ushort (*)[33])As;
                int wl = tid >> 3, c4 = (tid & 7) * 4;
                ushort4 v = *(const ushort4*)&g.vtsrc[((size_t)b * g.vtNw + w0 + wl) * 768 + 384 + c0 + c4];
                __syncthreads();   // protect LDS reuse from prior unit
                t[wl][c4] = v.x; t[wl][c4 + 1] = v.y; t[wl][c4 + 2] = v.z; t[wl][c4 + 3] = v.w;
                __syncthreads();
                int dl = tid >> 3, w4 = (tid & 7) * 4;
                ushort4 o;
                o.x = t[w4][dl]; o.y = t[w4 + 1][dl]; o.z = t[w4 + 2][dl]; o.w = t[w4 + 3][dl];
                *(ushort4*)&g.vtdst[((size_t)b * C_ + c0 + dl) * g.vtNw + w0 + w4] = o;
            }
            return;
        }
        // -------- fused p_t head: 2 rows per unit
        __shared__ float red[2][128];
        int flat = (bat - g.nbat - g.vtz) * per + bxy;
        int sub = tid >> 7, t = tid & 127;
        int row = flat * 2 + sub;
        float s = 0.f;
        if (row < g.ptrows) {
            const float* x = g.ptT + (size_t)row * C_;
            s = x[t] * g.vpw[t] + x[t + 128] * g.vpw[t + 128]
              + x[t + 256] * g.vpw[t + 256];
        }
        __syncthreads();   // protect LDS reuse from prior unit
        red[sub][t] = s;
        __syncthreads();
        if (row < g.ptrows && t < 64) {
            float s2 = red[sub][t] + red[sub][t + 64];
            for (int o = 32; o; o >>= 1) s2 += __shfl_down(s2, o);
            if (t == 0) g.ptout[row] = 512.0f / (1.0f + expf(-(s2 + g.vpb[0])));
        }
        return;
    }
    const int bn = bx * 64, bm = by * 64;
    const int bb = bat / g.NH, hh = bat % g.NH;
    const ushort* A  = g.A  + (size_t)bb * g.AsB + (size_t)hh * g.AsH;
    const ushort* Bt = g.Bt + (size_t)bb * g.BsB + (size_t)hh * g.BsH;
    const int wav = tid >> 6, lane = tid & 63;
    const int lrow = lane & 15, lq = lane >> 4;
    const int sr = tid >> 2, sc0 = (tid & 3) * 8;
    const ushort* Ag = A  + (size_t)(bm + sr) * g.lda + sc0;
    const ushort* Bg = Bt + (size_t)(bn + sr) * g.ldb + sc0;
    ushort* Asw = &As[sr * 40 + sc0];
    ushort* Bsw = &Bs[sr * 40 + sc0];

    floatx4 acc[4] = {};

    uint4 a = *(const uint4*)(Ag);
    uint4 b = *(const uint4*)(Bg);

    for (int k0 = 0; k0 < g.K; k0 += 32) {
        __syncthreads();
        *(uint4*)Asw = a; *(uint4*)Bsw = b;
        __syncthreads();
        if (k0 + 32 < g.K) {
            a = *(const uint4*)(Ag + k0 + 32);
            b = *(const uint4*)(Bg + k0 + 32);
        }
        short8 af = *(const short8*)&As[(wav * 16 + lrow) * 40 + lq * 8];
#pragma unroll
        for (int j = 0; j < 4; ++j) {
            short8 bf = *(const short8*)&Bs[(16 * j + lrow) * 40 + lq * 8];
            acc[j] = __builtin_amdgcn_mfma_f32_16x16x32_bf16(af, bf, acc[j], 0, 0, 0);
        }
    }

#pragma unroll
    for (int j = 0; j < 4; ++j) {
        int col = bn + 16 * j + lrow;
        float bv = g.bias ? g.bias[col] : 0.f;
        int row0 = bm + wav * 16 + lq * 4;
#pragma unroll
        for (int r = 0; r < 4; ++r) {
            float v = acc[j][r] * g.alpha + bv;
            if (g.act == 1) v = tanhf(v);
            size_t off = (size_t)bb * g.OsB + (size_t)hh * g.OsH
                       + (size_t)(row0 + r) * g.ldo + col;
            if (g.outF) g.outF[off] = v;
            if (g.outB) g.outB[off] = f2bf(v);
        }
    }
}

// ------------------------------------------- softmax (+ optional gauss) unit: 4 rows
struct SMArgs { const float* sc; const float* ptv; ushort* P; int mode; int units; };

template <int NW, int GAUSS>
static __device__ void sm_body(const SMArgs& a, int u) {
    int row = u * 4 + (threadIdx.x >> 6);
    int lane = threadIdx.x & 63;
    const float* s = a.sc + (size_t)row * NW;
    float pcen = GAUSS ? a.ptv[row] : 0.f;
    float vals[NW / 64];
    float m = -1e30f;
#pragma unroll
    for (int i = 0; i < NW / 64; ++i) {
        int w = lane + 64 * i;
        float v = s[w];
        if (GAUSS) { float dw = (float)w - pcen; v *= expf(dw * dw * (-1.0f / 18.0f)); }
        vals[i] = v; m = fmaxf(m, v);
    }
#pragma unroll
    for (int o = 32; o; o >>= 1) m = fmaxf(m, __shfl_xor(m, o));
    float sum = 0.f;
#pragma unroll
    for (int i = 0; i < NW / 64; ++i) { vals[i] = expf(vals[i] - m); sum += vals[i]; }
#pragma unroll
    for (int o = 32; o; o >>= 1) sum += __shfl_xor(sum, o);
    float rinv = 1.0f / sum;
    ushort* op = a.P + (size_t)row * NW;
#pragma unroll
    for (int i = 0; i < NW / 64; ++i) op[lane + 64 * i] = f2bf(vals[i] * rinv);
}

static __device__ void sm_unit(const SMArgs& a, int u) {
    if (a.mode == 0) sm_body<128, 0>(a, u);
    else if (a.mode == 1) sm_body<512, 0>(a, u);
    else sm_body<512, 1>(a, u);
}

// ------------------------------------------- persistent segment: QK -> SM -> PV -> proj
struct SegArgs {
    BGArgs g1; int u1, gx1, gy1;
    SMArgs sm;
    BGArgs g2; int u2, gx2, gy2;
    BGArgs g3; int u3, gx3, gy3;
    uint* bar;
};

__global__ __launch_bounds__(256, 2) void seg_kernel(SegArgs s) {
    const uint nb = gridDim.x;
    for (int u = blockIdx.x; u < s.u1; u += gridDim.x) battn_unit(s.g1, u, s.gx1, s.gy1);
    gridbar(s.bar, s.bar + 1, nb);
    for (int u = blockIdx.x; u < s.sm.units; u += gridDim.x) sm_unit(s.sm, u);
    gridbar(s.bar, s.bar + 1, nb);
    for (int u = blockIdx.x; u < s.u2; u += gridDim.x) battn_unit(s.g2, u, s.gx2, s.gy2);
    gridbar(s.bar, s.bar + 1, nb);
    for (int u = blockIdx.x; u < s.u3; u += gridDim.x) battn_unit(s.g3, u, s.gx3, s.gy3);
}

// host-side plan builder (mirrors old battn() launcher arithmetic)
struct BGPlan { BGArgs g; int units, gx, gy; };
static inline BGPlan planBG(const ushort* A, const ushort* Bt,
                            const float* bias, float* outF, ushort* outB,
                            int M, int N, int K, float alpha, int act,
                            int lda, long AsB, int AsH,
                            int ldb, long BsB, int BsH,
                            int ldo, long OsB, int OsH,
                            int NH, int nbat,
                            const ushort* vtsrc = nullptr, ushort* vtdst = nullptr,
                            int vtNw = 0,
                            const float* ptT = nullptr, const float* vpw = nullptr,
                            const float* vpb = nullptr, float* ptout = nullptr,
                            int ptrows = 0) {
    BGPlan p;
    BGArgs& g = p.g;
    g.A = A; g.Bt = Bt; g.bias = bias; g.outF = outF; g.outB = outB;
    g.lda = lda; g.ldb = ldb; g.ldo = ldo;
    g.AsB = AsB; g.BsB = BsB; g.OsB = OsB;
    g.AsH = AsH; g.BsH = BsH; g.OsH = OsH;
    g.K = K; g.NH = NH; g.alpha = alpha; g.act = act;
    g.nbat = nbat; g.vtsrc = vtsrc; g.vtdst = vtdst; g.vtNw = vtNw;
    g.ptT = ptT; g.vpw = vpw; g.vpb = vpb; g.ptout = ptout; g.ptrows = ptrows;
    p.gx = N / 64; p.gy = M / 64;
    int per = p.gx * p.gy;
    int vtz = 0, ptz = 0;
    if (vtsrc) {
        int nvt = B_ * (vtNw / 32) * (C_ / 32);
        vtz = (nvt + per - 1) / per;
    }
    if (ptT) {
        int npb = (ptrows + 1) / 2;
        ptz = (npb + per - 1) / per;
    }
    g.vtz = vtz;
    p.units = per * (nbat + vtz + ptz);
    return p;
}

static inline void launchSeg(hipStream_t st, const BGPlan& q, SMArgs sm,
                             const BGPlan& pv, const BGPlan& pr, uint* bar) {
    SegArgs s;
    s.g1 = q.g;  s.u1 = q.units;  s.gx1 = q.gx;  s.gy1 = q.gy;
    s.sm = sm;
    s.g2 = pv.g; s.u2 = pv.units; s.gx2 = pv.gx; s.gy2 = pv.gy;
    s.g3 = pr.g; s.u3 = pr.units; s.gx3 = pr.gx; s.gy3 = pr.gy;
    s.bar = bar;
    seg_kernel<<<dim3(512), dim3(256), 0, st>>>(s);
}

// ---------------------------------------------------------------- dual LayerNorm -> bf16
struct Ln2Desc {
    const void* X0; const float* g0; const float* b0; ushort* Y0; int bf0; int rows0;
    const void* X1; const float* g1; const float* b1; ushort* Y1; int bf1;
};
__global__ __launch_bounds__(128) void ln2_kernel(Ln2Desc d) {
    int row = blockIdx.x;
    const void* X; const float* g; const float* bb; ushort* Y; int isbf;
    if (row < d.rows0) { X = d.X0; g = d.g0; bb = d.b0; Y = d.Y0; isbf = d.bf0; }
    else { row -= d.rows0; X = d.X1; g = d.g1; bb = d.b1; Y = d.Y1; isbf = d.bf1; }
    const float*  xf = (const float*)X + (size_t)row * C_;
    const ushort* xb = (const ushort*)X + (size_t)row * C_;
    ushort* y = Y + (size_t)row * C_;
    int t = threadIdx.x;
    float v0, v1, v2;
    if (isbf) { v0 = ldf(xb, t); v1 = ldf(xb, t + 128); v2 = ldf(xb, t + 256); }
    else      { v0 = ldf(xf, t); v1 = ldf(xf, t + 128); v2 = ldf(xf, t + 256); }
    float s = v0 + v1 + v2, sq = v0 * v0 + v1 * v1 + v2 * v2;
    __shared__ float rs[128], rq[128];
    rs[t] = s; rq[t] = sq; __syncthreads();
    if (t < 64) {
        s = rs[t] + rs[t + 64]; sq = rq[t] + rq[t + 64];
        for (int o = 32; o; o >>= 1) { s += __shfl_down(s, o); sq += __shfl_down(sq, o); }
        if (t == 0) { rs[0] = s; rq[0] = sq; }
    }
    __syncthreads();
    float mean = rs[0] * (1.0f / C_);
    float var  = rq[0] * (1.0f / C_) - mean * mean;
    float inv  = rsqrtf(var + 1e-6f);
    y[t]       = f2bf((v0 - mean) * inv * g[t]       + bb[t]);
    y[t + 128] = f2bf((v1 - mean) * inv * g[t + 128] + bb[t + 128]);
    y[t + 256] = f2bf((v2 - mean) * inv * g[t + 256] + bb[t + 256]);
}

// ---------------------------------------------------------------- launch
extern "C" void kernel_launch(void* const* d_in, const int* in_sizes, int n_in,
                              void* d_out, int out_size, void* d_ws, size_t ws_size,
                              hipStream_t stream) {
    const float* q     = (const float*)d_in[0];
    const float* kv    = (const float*)d_in[1];
    const float* Wq    = (const float*)d_in[2];
    const float* Wkv   = (const float*)d_in[3];
    const float* Wproj = (const float*)d_in[4];
    const float* bproj = (const float*)d_in[5];
    const float* Wp_w  = (const float*)d_in[6];
    const float* Wp_b  = (const float*)d_in[7];
    const float* vp_w  = (const float*)d_in[8];
    const float* vp_b  = (const float*)d_in[9];
    const float* Wqpos = (const float*)d_in[10];
    const float* bqpos = (const float*)d_in[11];
    const float* Wrctc = (const float*)d_in[12];
    const float* brctc = (const float*)d_in[13];
    const float* ca1_Wq    = (const float*)d_in[14];
    const float* ca1_Wkv   = (const float*)d_in[15];
    const float* ca1_Wproj = (const float*)d_in[16];
    const float* ca1_bproj = (const float*)d_in[17];
    const float* ca2_Wq    = (const float*)d_in[18];
    const float* ca2_Wkv   = (const float*)d_in[19];
    const float* ca2_Wproj = (const float*)d_in[20];
    const float* ca2_bproj = (const float*)d_in[21];
    const float* g_q1  = (const float*)d_in[22];
    const float* b_q1  = (const float*)d_in[23];
    const float* g_kv1 = (const float*)d_in[24];
    const float* b_kv1 = (const float*)d_in[25];
    const float* g_q2  = (const float*)d_in[26];
    const float* b_q2  = (const float*)d_in[27];
    const float* g_kv2 = (const float*)d_in[28];
    const float* b_kv2 = (const float*)d_in[29];
    float* out = (float*)d_out;
    float* ws  = (float*)d_ws;

    // workspace layout (float offsets), total 34140160 fl ~ 136.6 MB
    ushort* dec0b = (ushort*)(ws);                   // 6291456 ush
    ushort* wb    = (ushort*)(ws + 3145728);         // 2211840 ush
    ushort* qb    = (ushort*)(ws + 4251648);         // 1572864 ush
    ushort* decb  = (ushort*)(ws + 5038080);         // 6291456 ush
    ushort* qhb   = (ushort*)(ws + 8183808);         // 1572864 ush
    float*  p     = ws + 8970240;                    // 1572864 fl
    ushort* pb    = (ushort*)(ws + 10543104);        // 1572864 ush
    float*  t1    = ws + 11329536;                   // 1572864 fl
    ushort* t1b   = (ushort*)(ws + 12902400);        // 1572864 ush
    ushort* t2b   = (ushort*)(ws + 13688832);        // 6291456 ush
    ushort* qpb   = (ushort*)(ws + 16834560);        // 1572864 ush
    ushort* kvb   = (ushort*)(ws + 17620992);        // 12582912 ush
    ushort* vt    = (ushort*)(ws + 23912448);        // 6291456 ush
    float*  sc    = ws + 27058176;                   // 4194304 fl
    ushort* Pb    = (ushort*)(ws + 31252480);        // 4194304 ush
    ushort* xb    = (ushort*)(ws + 33349632);        // 1572864 ush
    float*  ptb   = ws + 34136064;                   // 4096 fl
    // grid-barrier state lives at the start of dec0b (dead after J1); zeroed below.
    uint*   bar   = (uint*)dec0b;

    // bf16 transposed weight sub-offsets (ushort units)
    ushort* wbWq     = wb;
    ushort* wbWqpos  = wb + 147456;
    ushort* wbWrctc  = wb + 294912;
    ushort* wbC1Wq   = wb + 442368;
    ushort* wbC1Wp   = wb + 589824;
    ushort* wbC2Wq   = wb + 737280;
    ushort* wbC2Wp   = wb + 884736;
    ushort* wbWpw    = wb + 1032192;
    ushort* wbWproj  = wb + 1179648;
    ushort* wbWkv    = wb + 1327104;
    ushort* wbC1Wkv  = wb + 1622016;
    ushort* wbC2Wkv  = wb + 1916928;

    const float rs384 = 0.05103103630798288f;  // 1/sqrt(384)
    const float rs192 = 0.07216878364870323f;  // 1/sqrt(192)

    // 1. merged prep: mean over H, q cast, 12 weight transpose-casts
    {
        PrepDesc d;
        d.kv = kv; d.dec0b = dec0b; d.q = q; d.qb = qb;
        const float* s_[12] = {Wq, Wqpos, Wrctc, ca1_Wq, ca1_Wproj, ca2_Wq, ca2_Wproj,
                               Wp_w, Wproj, Wkv, ca1_Wkv, ca2_Wkv};
        ushort* t_[12] = {wbWq, wbWqpos, wbWrctc, wbC1Wq, wbC1Wp, wbC2Wq, wbC2Wp,
                          wbWpw, wbWproj, wbWkv, wbC1Wkv, wbC2Wkv};
        for (int i = 0; i < 12; ++i) {
            d.wsrc[i] = s_[i]; d.wdst[i] = t_[i];
            d.wN[i] = (i >= 9) ? 768 : 384;
        }
        prep2_kernel<<<6144 + 1536 + 3456, 256, 0, stream>>>(d);
    }
    // 2. J1: {dec = dec0@Wrctc, qh = (q@Wq)*rs384, p = q@Wqpos + bqpos}
    {
        GJob js[3];
        js[0] = {dec0b, wbWrctc, brctc, nullptr, decb, B_ * W_, 384, 384, 1.f, 0};
        js[1] = {qb, wbWq, nullptr, nullptr, qhb, B_ * S_, 384, 384, rs384, 0};
        js[2] = {qb, wbWqpos, bqpos, p, nullptr, B_ * S_, 384, 384, 1.f, 0};
        bgemmJ(stream, 3, js);
    }
    // 2b. zero the grid-barrier state (dec0b now dead)
    hipMemsetAsync(bar, 0, 64, stream);
    // 3. ca1 LN pair
    {
        Ln2Desc d;
        d.X0 = p; d.g0 = g_q1;  d.b0 = b_q1;  d.Y0 = t1b; d.bf0 = 0; d.rows0 = B_ * S_;
        d.X1 = q; d.g1 = g_kv1; d.b1 = b_kv1; d.Y1 = t2b; d.bf1 = 0;
        ln2_kernel<<<2 * B_ * S_, 128, 0, stream>>>(d);
    }
    // 4. J2: {ca1 qp, ca1 kv}
    {
        GJob js[2];
        js[0] = {t1b, wbC1Wq, nullptr, nullptr, qpb, B_ * S_, 384, 384, rs192, 0};
        js[1] = {t2b, wbC1Wkv, nullptr, nullptr, kvb, B_ * S_, 768, 384, 1.f, 0};
        bgemmJ(stream, 2, js);
    }
    // 5. SEG1: QK1(+vtrans) -> SM -> PV1 -> proj1
    {
        BGPlan qk = planBG(qpb, kvb, nullptr, sc, nullptr, 128, 128, 192, 1.f, 0,
                           384, (long)S_ * 384, 192,
                           768, (long)S_ * 768, 192,
                           128, (long)2 * S_ * 128, S_ * 128, 2, 64,
                           kvb, vt, S_);
        SMArgs sm = {sc, nullptr, Pb, 0, (B_ * 2 * S_) / 4};
        BGPlan pv = planBG(Pb, vt, nullptr, nullptr, xb, 128, 192, 128, 1.f, 0,
                           128, (long)2 * S_ * 128, S_ * 128,
                           128, (long)C_ * S_, 192 * S_,
                           384, (long)S_ * 384, 192, 2, 64);
        BGPlan pr = planBG(xb, wbC1Wp, ca1_bproj, p, nullptr, B_ * S_, 384, 384, 1.f, 0,
                           384, 0, 0, 384, 0, 0, 384, 0, 0, 1, 1);
        launchSeg(stream, qk, sm, pv, pr, bar);
    }
    // 6. ca2 LN pair
    {
        Ln2Desc d;
        d.X0 = p;    d.g0 = g_q2;  d.b0 = b_q2;  d.Y0 = t1b; d.bf0 = 0; d.rows0 = B_ * S_;
        d.X1 = decb; d.g1 = g_kv2; d.b1 = b_kv2; d.Y1 = t2b; d.bf1 = 1;
        ln2_kernel<<<B_ * S_ + B_ * W_, 128, 0, stream>>>(d);
    }
    // 7. J3: {ca2 qp, ca2 kv}
    {
        GJob js[2];
        js[0] = {t1b, wbC2Wq, nullptr, nullptr, qpb, B_ * S_, 384, 384, rs192, 0};
        js[1] = {t2b, wbC2Wkv, nullptr, nullptr, kvb, B_ * W_, 768, 384, 1.f, 0};
        bgemmJ(stream, 2, js);
    }
    // 8. SEG2: QK2(+vtrans) -> SM -> PV2 -> proj2 (p + pb)
    {
        BGPlan qk = planBG(qpb, kvb, nullptr, sc, nullptr, 128, 512, 192, 1.f, 0,
                           384, (long)S_ * 384, 192,
                           768, (long)W_ * 768, 192,
                           512, (long)2 * S_ * 512, S_ * 512, 2, 64,
                           kvb, vt, W_);
        SMArgs sm = {sc, nullptr, Pb, 1, (B_ * 2 * S_) / 4};
        BGPlan pv = planBG(Pb, vt, nullptr, nullptr, xb, 128, 192, 512, 1.f, 0,
                           512, (long)2 * S_ * 512, S_ * 512,
                           512, (long)C_ * W_, 192 * W_,
                           384, (long)S_ * 384, 192, 2, 64);
        BGPlan pr = planBG(xb, wbC2Wp, ca2_bproj, p, pb, B_ * S_, 384, 384, 1.f, 0,
                           384, 0, 0, 384, 0, 0, 384, 0, 0, 1, 1);
        launchSeg(stream, qk, sm, pv, pr, bar);
    }
    // 9. J4: {p_t tanh GEMM, main k/v = dec @ Wkv}
    {
        GJob js[2];
        js[0] = {pb, wbWpw, Wp_b, t1, nullptr, B_ * S_, 384, 384, 1.f, 1};
        js[1] = {decb, wbWkv, nullptr, nullptr, kvb, B_ * W_, 768, 384, 1.f, 0};
        bgemmJ(stream, 2, js);
    }
    // 10. SEG3: QKmain(+vtrans +pt head) -> gauss-SM -> PVmain -> out proj
    {
        BGPlan qk = planBG(qhb, kvb, nullptr, sc, nullptr, 128, 512, 384, 1.f, 0,
                           384, (long)S_ * 384, 0,
                           768, (long)W_ * 768, 0,
                           512, (long)S_ * 512, 0, 1, 32,
                           kvb, vt, W_,
                           t1, vp_w, vp_b, ptb, B_ * S_);
        SMArgs sm = {sc, ptb, Pb, 2, (B_ * S_) / 4};
        BGPlan pv = planBG(Pb, vt, nullptr, nullptr, xb, 128, 384, 512, 1.f, 0,
                           512, (long)S_ * 512, 0,
                           512, (long)C_ * W_, 0,
                           384, (long)S_ * 384, 0, 1, 32);
        BGPlan pr = planBG(xb, wbWproj, bproj, out, nullptr, B_ * S_, 384, 384, 1.f, 0,
                           384, 0, 0, 384, 0, 0, 384, 0, 0, 1, 1);
        launchSeg(stream, qk, sm, pv, pr, bar);
    }
}

// Round 9
// 555.947 us; speedup vs baseline: 1.7870x; 1.7870x over previous
//
#include <hip/hip_runtime.h>
#include <hip/hip_bf16.h>
#include <math.h>

#define B_ 32
#define S_ 128
#define C_ 384
#define H_ 8
#define W_ 512
#define NKV 4096   // H_*W_

typedef __attribute__((ext_vector_type(8))) short short8;
typedef __attribute__((ext_vector_type(4))) float floatx4;

static __device__ __forceinline__ ushort f2bf(float v) {
    __hip_bfloat16 h = __float2bfloat16(v);
    return *(ushort*)&h;
}
static __device__ __forceinline__ float ldf(const float* p, size_t i) { return p[i]; }
static __device__ __forceinline__ float ldf(const ushort* p, size_t i) {
    union { uint u; float f; } c; c.u = (uint)p[i] << 16; return c.f;
}

// ------------------------------------------- merged prep: mean, q cast, weight trans
struct PrepDesc {
    const float* kv; ushort* dec0b; const float* q; ushort* qb;
    const float* wsrc[12]; ushort* wdst[12]; int wN[12];
};
__global__ __launch_bounds__(256) void prep2_kernel(PrepDesc d) {
    __shared__ float t[32][33];
    const int meanB = B_ * W_ * (C_ / 4) / 256;   // 6144
    const int castB = B_ * S_ * (C_ / 4) / 256;   // 1536
    int bid = blockIdx.x;
    int tid = threadIdx.x;
    if (bid < meanB) {
        int v = bid * 256 + tid;
        int c4  = v % (C_ / 4);
        int row = v / (C_ / 4);
        int b = row / W_;
        int w = row % W_;
        const float4* src = (const float4*)d.kv + (size_t)(b * NKV + w) * (C_ / 4) + c4;
        float4 s = {0.f, 0.f, 0.f, 0.f};
#pragma unroll
        for (int h = 0; h < H_; ++h) {
            float4 x = src[(size_t)h * W_ * (C_ / 4)];
            s.x += x.x; s.y += x.y; s.z += x.z; s.w += x.w;
        }
        ushort4 o;
        o.x = f2bf(s.x * 0.125f); o.y = f2bf(s.y * 0.125f);
        o.z = f2bf(s.z * 0.125f); o.w = f2bf(s.w * 0.125f);
        ((ushort4*)d.dec0b)[v] = o;
        return;
    }
    if (bid < meanB + castB) {
        int v = (bid - meanB) * 256 + tid;
        float4 f = ((const float4*)d.q)[v];
        ushort4 o;
        o.x = f2bf(f.x); o.y = f2bf(f.y); o.z = f2bf(f.z); o.w = f2bf(f.w);
        ((ushort4*)d.qb)[v] = o;
        return;
    }
    int f = bid - meanB - castB;          // 0..3455
    int wi = f / 288, tile = f % 288;
    int N = d.wN[wi];
    int tiles_n = N / 32;
    if (tile >= 12 * tiles_n) return;     // K/32 == 12
    int k0 = (tile / tiles_n) * 32, n0 = (tile % tiles_n) * 32;
    int r = tid >> 3, c4 = (tid & 7) * 4;
    float4 v = *(const float4*)&d.wsrc[wi][(size_t)(k0 + r) * N + n0 + c4];
    t[r][c4] = v.x; t[r][c4 + 1] = v.y; t[r][c4 + 2] = v.z; t[r][c4 + 3] = v.w;
    __syncthreads();
    int c = tid >> 3, k4 = (tid & 7) * 4;
    ushort4 o;
    o.x = f2bf(t[k4][c]); o.y = f2bf(t[k4 + 1][c]);
    o.z = f2bf(t[k4 + 2][c]); o.w = f2bf(t[k4 + 3][c]);
    *(ushort4*)&d.wdst[wi][(size_t)(n0 + c) * 384 + k0 + k4] = o;
}

// ---------------------------------------------------------------- bf16 MFMA GEMM 128x128
// Reg-staged 128x128 + job table (up to 3 GEMMs / dispatch) + K-loop software pipeline.
struct GJob {
    const ushort* A; const ushort* Bt;
    const float* bias; float* Cout; ushort* Cbf;
    int M, N, K; float alpha; int act;
};
struct GJobs { GJob j[3]; };

__global__ __launch_bounds__(256) void bgemm_kernel(GJobs gs) {
    const GJob g = gs.j[blockIdx.z];
    const int bm = blockIdx.y * 128, bn = blockIdx.x * 128;
    if (bm >= g.M || bn >= g.N) return;
    __shared__ ushort As[128 * 40];
    __shared__ ushort Bs[128 * 40];
    const int tid = threadIdx.x;
    const int wav = tid >> 6, lane = tid & 63;
    const int wm = (wav >> 1) * 64, wn = (wav & 1) * 64;
    const int lrow = lane & 15, lq = lane >> 4;

    floatx4 acc[4][4] = {};

    const int sr = tid >> 1, sc0 = (tid & 1) * 16;
    const ushort* Ag = g.A + (size_t)(bm + sr) * g.K + sc0;
    const ushort* Bg = g.Bt + (size_t)(bn + sr) * g.K + sc0;
    ushort* Asw = &As[sr * 40 + sc0];
    ushort* Bsw = &Bs[sr * 40 + sc0];

    uint4 a0 = *(const uint4*)(Ag);
    uint4 a1 = *(const uint4*)(Ag + 8);
    uint4 b0 = *(const uint4*)(Bg);
    uint4 b1 = *(const uint4*)(Bg + 8);

    for (int k0 = 0; k0 < g.K; k0 += 32) {
        __syncthreads();
        *(uint4*)Asw = a0; *(uint4*)(Asw + 8) = a1;
        *(uint4*)Bsw = b0; *(uint4*)(Bsw + 8) = b1;
        __syncthreads();
        if (k0 + 32 < g.K) {
            a0 = *(const uint4*)(Ag + k0 + 32);
            a1 = *(const uint4*)(Ag + k0 + 40);
            b0 = *(const uint4*)(Bg + k0 + 32);
            b1 = *(const uint4*)(Bg + k0 + 40);
        }
        short8 af[4], bfr[4];
#pragma unroll
        for (int i = 0; i < 4; ++i)
            af[i] = *(const short8*)&As[(wm + 16 * i + lrow) * 40 + lq * 8];
#pragma unroll
        for (int j = 0; j < 4; ++j)
            bfr[j] = *(const short8*)&Bs[(wn + 16 * j + lrow) * 40 + lq * 8];
#pragma unroll
        for (int i = 0; i < 4; ++i)
#pragma unroll
            for (int j = 0; j < 4; ++j)
                acc[i][j] = __builtin_amdgcn_mfma_f32_16x16x32_bf16(af[i], bfr[j], acc[i][j], 0, 0, 0);
    }

#pragma unroll
    for (int i = 0; i < 4; ++i)
#pragma unroll
        for (int j = 0; j < 4; ++j) {
            int row = bm + wm + 16 * i + lq * 4;
            int col = bn + wn + 16 * j + lrow;
            float bv = g.bias ? g.bias[col] : 0.f;
#pragma unroll
            for (int r = 0; r < 4; ++r) {
                float v = acc[i][j][r] * g.alpha + bv;
                if (g.act == 1) v = tanhf(v);
                size_t off = (size_t)(row + r) * g.N + col;
                if (g.Cout) g.Cout[off] = v;
                if (g.Cbf) g.Cbf[off] = f2bf(v);
            }
        }
}

static inline void bgemmJ(hipStream_t st, int nj, const GJob* js) {
    GJobs gs;
    int mx = 0, my = 0;
    for (int i = 0; i < nj; ++i) {
        gs.j[i] = js[i];
        int nx = js[i].N / 128, ny = js[i].M / 128;
        if (nx > mx) mx = nx;
        if (ny > my) my = ny;
    }
    for (int i = nj; i < 3; ++i) gs.j[i] = js[0];
    bgemm_kernel<<<dim3(mx, my, nj), 256, 0, st>>>(gs);
}

// ------------------------------------------- generic batched 64x64 MFMA GEMM
// + K-loop software pipeline + optional fused 32x32 v-transpose blocks and fused
// p_t-head row-reductions packed into extra blockIdx.z slices (flat-indexed).
struct BGArgs {
    const ushort* A; const ushort* Bt;
    const float* bias; float* outF; ushort* outB;
    int lda, ldb, ldo;
    long AsB, BsB, OsB;
    int AsH, BsH, OsH;
    int K, NH;
    float alpha; int act;
    int nbat, vtz;
    const ushort* vtsrc; ushort* vtdst; int vtNw;
    const float* ptT; const float* vpw; const float* vpb; float* ptout; int ptrows;
};
__global__ __launch_bounds__(256) void battn_kernel(BGArgs g) {
    __shared__ ushort As[64 * 40];
    __shared__ ushort Bs[64 * 40];
    const int tid = threadIdx.x;
    const int bat = blockIdx.z;
    if (bat >= g.nbat) {
        int per = gridDim.x * gridDim.y;
        int bxy = blockIdx.y * gridDim.x + blockIdx.x;
        if (bat < g.nbat + g.vtz) {
            // -------- fused v-transpose tile: kvb (B*Nw,768) v-part -> vt (B,384,Nw)
            int flat = (bat - g.nbat) * per + bxy;
            int wt_n = g.vtNw >> 5;
            int tiles = wt_n * (C_ / 32);
            if (flat >= B_ * tiles) return;
            int b  = flat / tiles, rr = flat % tiles;
            int w0 = (rr % wt_n) * 32, c0 = (rr / wt_n) * 32;
            ushort (*t)[33] = (ushort (*)[33])As;
            int wl = tid >> 3, c4 = (tid & 7) * 4;
            ushort4 v = *(const ushort4*)&g.vtsrc[((size_t)b * g.vtNw + w0 + wl) * 768 + 384 + c0 + c4];
            t[wl][c4] = v.x; t[wl][c4 + 1] = v.y; t[wl][c4 + 2] = v.z; t[wl][c4 + 3] = v.w;
            __syncthreads();
            int dl = tid >> 3, w4 = (tid & 7) * 4;
            ushort4 o;
            o.x = t[w4][dl]; o.y = t[w4 + 1][dl]; o.z = t[w4 + 2][dl]; o.w = t[w4 + 3][dl];
            *(ushort4*)&g.vtdst[((size_t)b * C_ + c0 + dl) * g.vtNw + w0 + w4] = o;
            return;
        }
        // -------- fused p_t head: 2 rows per block (sub-half of 128 threads each)
        __shared__ float red[2][128];
        int flat = (bat - g.nbat - g.vtz) * per + bxy;
        int sub = tid >> 7, t = tid & 127;
        int row = flat * 2 + sub;
        if (row < g.ptrows) {
            const float* x = g.ptT + (size_t)row * C_;
            float s = x[t] * g.vpw[t] + x[t + 128] * g.vpw[t + 128]
                    + x[t + 256] * g.vpw[t + 256];
            red[sub][t] = s;
        }
        __syncthreads();
        if (row < g.ptrows && t < 64) {
            float s = red[sub][t] + red[sub][t + 64];
            for (int o = 32; o; o >>= 1) s += __shfl_down(s, o);
            if (t == 0) g.ptout[row] = 512.0f / (1.0f + expf(-(s + g.vpb[0])));
        }
        return;
    }
    const int bn = blockIdx.x * 64, bm = blockIdx.y * 64;
    const int bb = bat / g.NH, hh = bat % g.NH;
    const ushort* A  = g.A  + (size_t)bb * g.AsB + (size_t)hh * g.AsH;
    const ushort* Bt = g.Bt + (size_t)bb * g.BsB + (size_t)hh * g.BsH;
    const int wav = tid >> 6, lane = tid & 63;
    const int lrow = lane & 15, lq = lane >> 4;
    const int sr = tid >> 2, sc0 = (tid & 3) * 8;
    const ushort* Ag = A  + (size_t)(bm + sr) * g.lda + sc0;
    const ushort* Bg = Bt + (size_t)(bn + sr) * g.ldb + sc0;
    ushort* Asw = &As[sr * 40 + sc0];
    ushort* Bsw = &Bs[sr * 40 + sc0];

    floatx4 acc[4] = {};

    uint4 a = *(const uint4*)(Ag);
    uint4 b = *(const uint4*)(Bg);

    for (int k0 = 0; k0 < g.K; k0 += 32) {
        __syncthreads();
        *(uint4*)Asw = a; *(uint4*)Bsw = b;
        __syncthreads();
        if (k0 + 32 < g.K) {
            a = *(const uint4*)(Ag + k0 + 32);
            b = *(const uint4*)(Bg + k0 + 32);
        }
        short8 af = *(const short8*)&As[(wav * 16 + lrow) * 40 + lq * 8];
#pragma unroll
        for (int j = 0; j < 4; ++j) {
            short8 bf = *(const short8*)&Bs[(16 * j + lrow) * 40 + lq * 8];
            acc[j] = __builtin_amdgcn_mfma_f32_16x16x32_bf16(af, bf, acc[j], 0, 0, 0);
        }
    }

#pragma unroll
    for (int j = 0; j < 4; ++j) {
        int col = bn + 16 * j + lrow;
        float bv = g.bias ? g.bias[col] : 0.f;
        int row0 = bm + wav * 16 + lq * 4;
#pragma unroll
        for (int r = 0; r < 4; ++r) {
            float v = acc[j][r] * g.alpha + bv;
            if (g.act == 1) v = tanhf(v);
            size_t off = (size_t)bb * g.OsB + (size_t)hh * g.OsH
                       + (size_t)(row0 + r) * g.ldo + col;
            if (g.outF) g.outF[off] = v;
            if (g.outB) g.outB[off] = f2bf(v);
        }
    }
}

static inline void battn(hipStream_t st, const ushort* A, const ushort* Bt,
                         const float* bias, float* outF, ushort* outB,
                         int M, int N, int K, float alpha, int act,
                         int lda, long AsB, int AsH,
                         int ldb, long BsB, int BsH,
                         int ldo, long OsB, int OsH,
                         int NH, int nbat,
                         const ushort* vtsrc = nullptr, ushort* vtdst = nullptr,
                         int vtNw = 0,
                         const float* ptT = nullptr, const float* vpw = nullptr,
                         const float* vpb = nullptr, float* ptout = nullptr,
                         int ptrows = 0) {
    BGArgs g;
    g.A = A; g.Bt = Bt; g.bias = bias; g.outF = outF; g.outB = outB;
    g.lda = lda; g.ldb = ldb; g.ldo = ldo;
    g.AsB = AsB; g.BsB = BsB; g.OsB = OsB;
    g.AsH = AsH; g.BsH = BsH; g.OsH = OsH;
    g.K = K; g.NH = NH; g.alpha = alpha; g.act = act;
    g.nbat = nbat; g.vtsrc = vtsrc; g.vtdst = vtdst; g.vtNw = vtNw;
    g.ptT = ptT; g.vpw = vpw; g.vpb = vpb; g.ptout = ptout; g.ptrows = ptrows;
    int gx = N / 64, gy = M / 64;
    int per = gx * gy;
    int vtz = 0, ptz = 0;
    if (vtsrc) {
        int nvt = B_ * (vtNw / 32) * (C_ / 32);
        vtz = (nvt + per - 1) / per;
    }
    if (ptT) {
        int npb = (ptrows + 1) / 2;
        ptz = (npb + per - 1) / per;
    }
    g.vtz = vtz;
    battn_kernel<<<dim3(gx, gy, nbat + vtz + ptz), 256, 0, st>>>(g);
}

static inline void bgemm64(hipStream_t st, const ushort* A, const ushort* Bt,
                           const float* bias, float* outF, ushort* outB,
                           int M, int N, int K, float alpha, int act) {
    battn(st, A, Bt, bias, outF, outB, M, N, K, alpha, act,
          K, 0, 0, K, 0, 0, N, 0, 0, 1, 1);
}

// ---------------------------------------------------------------- dual LayerNorm -> bf16
struct Ln2Desc {
    const void* X0; const float* g0; const float* b0; ushort* Y0; int bf0; int rows0;
    const void* X1; const float* g1; const float* b1; ushort* Y1; int bf1;
};
__global__ __launch_bounds__(128) void ln2_kernel(Ln2Desc d) {
    int row = blockIdx.x;
    const void* X; const float* g; const float* bb; ushort* Y; int isbf;
    if (row < d.rows0) { X = d.X0; g = d.g0; bb = d.b0; Y = d.Y0; isbf = d.bf0; }
    else { row -= d.rows0; X = d.X1; g = d.g1; bb = d.b1; Y = d.Y1; isbf = d.bf1; }
    const float*  xf = (const float*)X + (size_t)row * C_;
    const ushort* xb = (const ushort*)X + (size_t)row * C_;
    ushort* y = Y + (size_t)row * C_;
    int t = threadIdx.x;
    float v0, v1, v2;
    if (isbf) { v0 = ldf(xb, t); v1 = ldf(xb, t + 128); v2 = ldf(xb, t + 256); }
    else      { v0 = ldf(xf, t); v1 = ldf(xf, t + 128); v2 = ldf(xf, t + 256); }
    float s = v0 + v1 + v2, sq = v0 * v0 + v1 * v1 + v2 * v2;
    __shared__ float rs[128], rq[128];
    rs[t] = s; rq[t] = sq; __syncthreads();
    if (t < 64) {
        s = rs[t] + rs[t + 64]; sq = rq[t] + rq[t + 64];
        for (int o = 32; o; o >>= 1) { s += __shfl_down(s, o); sq += __shfl_down(sq, o); }
        if (t == 0) { rs[0] = s; rq[0] = sq; }
    }
    __syncthreads();
    float mean = rs[0] * (1.0f / C_);
    float var  = rq[0] * (1.0f / C_) - mean * mean;
    float inv  = rsqrtf(var + 1e-6f);
    y[t]       = f2bf((v0 - mean) * inv * g[t]       + bb[t]);
    y[t + 128] = f2bf((v1 - mean) * inv * g[t + 128] + bb[t + 128]);
    y[t + 256] = f2bf((v2 - mean) * inv * g[t + 256] + bb[t + 256]);
}

// ------------------------------------------- softmax (+ optional gauss) rows
template <int NW, int GAUSS>
__global__ __launch_bounds__(256) void softmax_kernel(
    const float* __restrict__ sc, const float* __restrict__ ptv,
    ushort* __restrict__ P)
{
    int row = blockIdx.x * 4 + (threadIdx.x >> 6);
    int lane = threadIdx.x & 63;
    const float* s = sc + (size_t)row * NW;
    float pcen = GAUSS ? ptv[row] : 0.f;
    float vals[NW / 64];
    float m = -1e30f;
#pragma unroll
    for (int i = 0; i < NW / 64; ++i) {
        int w = lane + 64 * i;
        float v = s[w];
        if (GAUSS) { float dw = (float)w - pcen; v *= expf(dw * dw * (-1.0f / 18.0f)); }
        vals[i] = v; m = fmaxf(m, v);
    }
#pragma unroll
    for (int o = 32; o; o >>= 1) m = fmaxf(m, __shfl_xor(m, o));
    float sum = 0.f;
#pragma unroll
    for (int i = 0; i < NW / 64; ++i) { vals[i] = expf(vals[i] - m); sum += vals[i]; }
#pragma unroll
    for (int o = 32; o; o >>= 1) sum += __shfl_xor(sum, o);
    float rinv = 1.0f / sum;
    ushort* op = P + (size_t)row * NW;
#pragma unroll
    for (int i = 0; i < NW / 64; ++i) op[lane + 64 * i] = f2bf(vals[i] * rinv);
}

// ---------------------------------------------------------------- launch
extern "C" void kernel_launch(void* const* d_in, const int* in_sizes, int n_in,
                              void* d_out, int out_size, void* d_ws, size_t ws_size,
                              hipStream_t stream) {
    const float* q     = (const float*)d_in[0];
    const float* kv    = (const float*)d_in[1];
    const float* Wq    = (const float*)d_in[2];
    const float* Wkv   = (const float*)d_in[3];
    const float* Wproj = (const float*)d_in[4];
    const float* bproj = (const float*)d_in[5];
    const float* Wp_w  = (const float*)d_in[6];
    const float* Wp_b  = (const float*)d_in[7];
    const float* vp_w  = (const float*)d_in[8];
    const float* vp_b  = (const float*)d_in[9];
    const float* Wqpos = (const float*)d_in[10];
    const float* bqpos = (const float*)d_in[11];
    const float* Wrctc = (const float*)d_in[12];
    const float* brctc = (const float*)d_in[13];
    const float* ca1_Wq    = (const float*)d_in[14];
    const float* ca1_Wkv   = (const float*)d_in[15];
    const float* ca1_Wproj = (const float*)d_in[16];
    const float* ca1_bproj = (const float*)d_in[17];
    const float* ca2_Wq    = (const float*)d_in[18];
    const float* ca2_Wkv   = (const float*)d_in[19];
    const float* ca2_Wproj = (const float*)d_in[20];
    const float* ca2_bproj = (const float*)d_in[21];
    const float* g_q1  = (const float*)d_in[22];
    const float* b_q1  = (const float*)d_in[23];
    const float* g_kv1 = (const float*)d_in[24];
    const float* b_kv1 = (const float*)d_in[25];
    const float* g_q2  = (const float*)d_in[26];
    const float* b_q2  = (const float*)d_in[27];
    const float* g_kv2 = (const float*)d_in[28];
    const float* b_kv2 = (const float*)d_in[29];
    float* out = (float*)d_out;
    float* ws  = (float*)d_ws;

    // workspace layout (float offsets), total 34140160 fl ~ 136.6 MB
    ushort* dec0b = (ushort*)(ws);                   // 6291456 ush
    ushort* wb    = (ushort*)(ws + 3145728);         // 2211840 ush
    ushort* qb    = (ushort*)(ws + 4251648);         // 1572864 ush
    ushort* decb  = (ushort*)(ws + 5038080);         // 6291456 ush
    ushort* qhb   = (ushort*)(ws + 8183808);         // 1572864 ush
    float*  p     = ws + 8970240;                    // 1572864 fl
    ushort* pb    = (ushort*)(ws + 10543104);        // 1572864 ush
    float*  t1    = ws + 11329536;                   // 1572864 fl
    ushort* t1b   = (ushort*)(ws + 12902400);        // 1572864 ush
    ushort* t2b   = (ushort*)(ws + 13688832);        // 6291456 ush
    ushort* qpb   = (ushort*)(ws + 16834560);        // 1572864 ush
    ushort* kvb   = (ushort*)(ws + 17620992);        // 12582912 ush
    ushort* vt    = (ushort*)(ws + 23912448);        // 6291456 ush
    float*  sc    = ws + 27058176;                   // 4194304 fl
    ushort* Pb    = (ushort*)(ws + 31252480);        // 4194304 ush
    ushort* xb    = (ushort*)(ws + 33349632);        // 1572864 ush
    float*  ptb   = ws + 34136064;                   // 4096 fl

    // bf16 transposed weight sub-offsets (ushort units)
    ushort* wbWq     = wb;
    ushort* wbWqpos  = wb + 147456;
    ushort* wbWrctc  = wb + 294912;
    ushort* wbC1Wq   = wb + 442368;
    ushort* wbC1Wp   = wb + 589824;
    ushort* wbC2Wq   = wb + 737280;
    ushort* wbC2Wp   = wb + 884736;
    ushort* wbWpw    = wb + 1032192;
    ushort* wbWproj  = wb + 1179648;
    ushort* wbWkv    = wb + 1327104;
    ushort* wbC1Wkv  = wb + 1622016;
    ushort* wbC2Wkv  = wb + 1916928;

    const float rs384 = 0.05103103630798288f;  // 1/sqrt(384)
    const float rs192 = 0.07216878364870323f;  // 1/sqrt(192)

    // 1. merged prep: mean over H, q cast, 12 weight transpose-casts
    {
        PrepDesc d;
        d.kv = kv; d.dec0b = dec0b; d.q = q; d.qb = qb;
        const float* s_[12] = {Wq, Wqpos, Wrctc, ca1_Wq, ca1_Wproj, ca2_Wq, ca2_Wproj,
                               Wp_w, Wproj, Wkv, ca1_Wkv, ca2_Wkv};
        ushort* t_[12] = {wbWq, wbWqpos, wbWrctc, wbC1Wq, wbC1Wp, wbC2Wq, wbC2Wp,
                          wbWpw, wbWproj, wbWkv, wbC1Wkv, wbC2Wkv};
        for (int i = 0; i < 12; ++i) {
            d.wsrc[i] = s_[i]; d.wdst[i] = t_[i];
            d.wN[i] = (i >= 9) ? 768 : 384;
        }
        prep2_kernel<<<6144 + 1536 + 3456, 256, 0, stream>>>(d);
    }
    // 2. J1: {dec = dec0@Wrctc, qh = (q@Wq)*rs384, p = q@Wqpos + bqpos}
    {
        GJob js[3];
        js[0] = {dec0b, wbWrctc, brctc, nullptr, decb, B_ * W_, 384, 384, 1.f, 0};
        js[1] = {qb, wbWq, nullptr, nullptr, qhb, B_ * S_, 384, 384, rs384, 0};
        js[2] = {qb, wbWqpos, bqpos, p, nullptr, B_ * S_, 384, 384, 1.f, 0};
        bgemmJ(stream, 3, js);
    }
    // 3. ca1
    {
        Ln2Desc d;
        d.X0 = p; d.g0 = g_q1;  d.b0 = b_q1;  d.Y0 = t1b; d.bf0 = 0; d.rows0 = B_ * S_;
        d.X1 = q; d.g1 = g_kv1; d.b1 = b_kv1; d.Y1 = t2b; d.bf1 = 0;
        ln2_kernel<<<2 * B_ * S_, 128, 0, stream>>>(d);
    }
    {
        GJob js[2];
        js[0] = {t1b, wbC1Wq, nullptr, nullptr, qpb, B_ * S_, 384, 384, rs192, 0};
        js[1] = {t2b, wbC1Wkv, nullptr, nullptr, kvb, B_ * S_, 768, 384, 1.f, 0};
        bgemmJ(stream, 2, js);
    }
    battn(stream, qpb, kvb, nullptr, sc, nullptr, 128, 128, 192, 1.f, 0,
          384, (long)S_ * 384, 192,
          768, (long)S_ * 768, 192,
          128, (long)2 * S_ * 128, S_ * 128, 2, 64,
          kvb, vt, S_);
    softmax_kernel<128, 0><<<(B_ * 2 * S_) / 4, 256, 0, stream>>>(sc, nullptr, Pb);
    battn(stream, Pb, vt, nullptr, nullptr, xb, 128, 192, 128, 1.f, 0,
          128, (long)2 * S_ * 128, S_ * 128,
          128, (long)C_ * S_, 192 * S_,
          384, (long)S_ * 384, 192, 2, 64);
    bgemm64(stream, xb, wbC1Wp, ca1_bproj, p, nullptr, B_ * S_, 384, 384, 1.f, 0);
    // 4. ca2
    {
        Ln2Desc d;
        d.X0 = p;    d.g0 = g_q2;  d.b0 = b_q2;  d.Y0 = t1b; d.bf0 = 0; d.rows0 = B_ * S_;
        d.X1 = decb; d.g1 = g_kv2; d.b1 = b_kv2; d.Y1 = t2b; d.bf1 = 1;
        ln2_kernel<<<B_ * S_ + B_ * W_, 128, 0, stream>>>(d);
    }
    {
        GJob js[2];
        js[0] = {t1b, wbC2Wq, nullptr, nullptr, qpb, B_ * S_, 384, 384, rs192, 0};
        js[1] = {t2b, wbC2Wkv, nullptr, nullptr, kvb, B_ * W_, 768, 384, 1.f, 0};
        bgemmJ(stream, 2, js);
    }
    battn(stream, qpb, kvb, nullptr, sc, nullptr, 128, 512, 192, 1.f, 0,
          384, (long)S_ * 384, 192,
          768, (long)W_ * 768, 192,
          512, (long)2 * S_ * 512, S_ * 512, 2, 64,
          kvb, vt, W_);
    softmax_kernel<512, 0><<<(B_ * 2 * S_) / 4, 256, 0, stream>>>(sc, nullptr, Pb);
    battn(stream, Pb, vt, nullptr, nullptr, xb, 128, 192, 512, 1.f, 0,
          512, (long)2 * S_ * 512, S_ * 512,
          512, (long)C_ * W_, 192 * W_,
          384, (long)S_ * 384, 192, 2, 64);
    bgemm64(stream, xb, wbC2Wp, ca2_bproj, p, pb, B_ * S_, 384, 384, 1.f, 0);
    // 5. J4: {p_t tanh GEMM, main k/v = dec @ Wkv}
    {
        GJob js[2];
        js[0] = {pb, wbWpw, Wp_b, t1, nullptr, B_ * S_, 384, 384, 1.f, 1};
        js[1] = {decb, wbWkv, nullptr, nullptr, kvb, B_ * W_, 768, 384, 1.f, 0};
        bgemmJ(stream, 2, js);
    }
    // 6. main attention: scores (+fused vtrans +fused p_t head), gauss-softmax, PV
    battn(stream, qhb, kvb, nullptr, sc, nullptr, 128, 512, 384, 1.f, 0,
          384, (long)S_ * 384, 0,
          768, (long)W_ * 768, 0,
          512, (long)S_ * 512, 0, 1, 32,
          kvb, vt, W_,
          t1, vp_w, vp_b, ptb, B_ * S_);
    softmax_kernel<512, 1><<<(B_ * S_) / 4, 256, 0, stream>>>(sc, ptb, Pb);
    battn(stream, Pb, vt, nullptr, nullptr, xb, 128, 384, 512, 1.f, 0,
          512, (long)S_ * 512, 0,
          512, (long)C_ * W_, 0,
          384, (long)S_ * 384, 0, 1, 32);
    // 7. out = x @ Wproj + bproj (fp32)
    bgemm64(stream, xb, wbWproj, bproj, out, nullptr, B_ * S_, 384, 384, 1.f, 0);
}